// Round 12
// baseline (162.712 us; speedup 1.0000x reference)
//
#include <hip/hip_runtime.h>

// B=8, T=2048, D_MODEL=1024, D_HEAD=64, fp32 in/out.
// pack   -> Wt bf16[192][1024]
// gemm   -> K-SPLIT 2: grid (512 m-tiles x 2 k-slices), 8 K-iters each, A+B via
//           global_load_lds + XOR swizzle; fp32 partial C [2][16384][192] (no atomics)
// reduce -> sum 2 slices, Q log2-scale, emit qkvqk bf16[16384][128] + vT[8][64][2048]
// attn   -> split-K no-max log2 flash; 128-row q-supertile x 256-key chunk (R10)
// combine-> weight-1 merge of <=8 chunks per (b, 64-row q-tile)
#define TT   2048
#define DM   1024
#define DH   64
#define NB   8
#define KS   512   // K per gemm slice
#define KST  72    // p_lds row stride (elems)

typedef __attribute__((ext_vector_type(4))) float          f32x4;
typedef __attribute__((ext_vector_type(4))) int            i32x4;
typedef __attribute__((ext_vector_type(4))) unsigned short u16x4;
typedef __attribute__((ext_vector_type(8))) short          s16x8;  // bf16x8 frag (4 VGPRs)

__device__ __forceinline__ unsigned short f2bf(float f) {  // RNE fp32->bf16
  unsigned int u = __float_as_uint(f);
  u += 0x7fffu + ((u >> 16) & 1u);
  return (unsigned short)(u >> 16);
}

#define MFMA(acc, a, b) \
  (acc) = __builtin_amdgcn_mfma_f32_16x16x32_bf16((a), (b), (acc), 0, 0, 0)

// Async global->LDS DMA, 16B/lane. LDS dest is wave-uniform base + lane*16.
__device__ __forceinline__ void gload_lds16(const void* g, void* l) {
  __builtin_amdgcn_global_load_lds(
      (const __attribute__((address_space(1))) void*)g,
      (__attribute__((address_space(3))) void*)l, 16, 0, 0);
}

// ws layout (bytes)
#define WS_WT    0u
#define WS_QK    393216u     // 16384*128*2 = 4,194,304
#define WS_VT    4587520u    // 8*64*2048*2 = 2,097,152
#define WS_OP    6684672u    // 8*144*4096*2 = 9,437,184 (bf16 partial O)
#define WS_ML    16121856u   // 8*144*64*4  = 294,912   (f32 l per row)
#define WS_P     16416768u   // 2*16384*192*4 = 25,165,824 (fp32 gemm partials)

// ---------------- pack: W_Q|W_K|W_V fp32[1024][64] -> Wt bf16[192][1024] -------------
__global__ __launch_bounds__(256) void pack_w_kernel(
    const float* __restrict__ wq, const float* __restrict__ wk,
    const float* __restrict__ wv, unsigned short* __restrict__ wt) {
  int idx = blockIdx.x * 256 + threadIdx.x;
  if (idx >= 192 * DM) return;
  int n = idx >> 10;
  int k = idx & (DM - 1);
  const float* src = (n < 64) ? wq : ((n < 128) ? wk : wv);
  wt[(size_t)n * DM + k] = f2bf(src[(size_t)k * DH + (n & 63)]);
}

// ---------------- QKV GEMM: K-split 2, A+B DMA-staged, fp32 partial out --------------
// blockIdx.x = m-tile (32 rows), blockIdx.y = k-slice. 1024 blocks -> 4 blocks/CU,
// 16 waves/CU; 8 K-iterations per block (half the exposed drain latencies of R10).
__global__ __launch_bounds__(256) void qkv_gemm_kernel(
    const float* __restrict__ x, const unsigned short* __restrict__ wt,
    float* __restrict__ pbuf) {
  __shared__ __align__(16) float          a_lds[32 * 64];    // 8 KB, swizzled chunks
  __shared__ __align__(16) unsigned short b_lds[192 * 64];   // 24 KB, swizzled chunks

  const int tid  = threadIdx.x;
  const int lane = tid & 63;
  const int w    = tid >> 6;
  const int ln   = lane & 15;
  const int quad = lane >> 4;
  const int mw   = w & 1;
  const int nw   = w >> 1;
  const int m0   = blockIdx.x * 32;
  const int n0   = nw * 96;
  const int ks0  = blockIdx.y * KS;
  const int lsw  = ln & 7;          // read-side swizzle key

  int agoff[2];
  #pragma unroll
  for (int i = 0; i < 2; ++i) {
    int s = i * 256 + w * 64 + lane;
    int m = s >> 4, cc = s & 15;                 // A: 16 chunks/row (16B = 4 fp32)
    agoff[i] = (m0 + m) * DM + ks0 + ((cc ^ (m & 7)) << 2);
  }
  int bgoff[6];
  #pragma unroll
  for (int j = 0; j < 6; ++j) {
    int s = j * 256 + w * 64 + lane;
    int n = s >> 3, cc = s & 7;                  // B: 8 chunks/row (16B = 8 bf16)
    bgoff[j] = n * DM + ks0 + ((cc ^ (n & 7)) << 3);
  }

  f32x4 acc[6];
  #pragma unroll
  for (int i = 0; i < 6; ++i) acc[i] = (f32x4){0.f, 0.f, 0.f, 0.f};
  union { s16x8 v; unsigned short h[8]; } ap;

  #pragma unroll
  for (int i = 0; i < 2; ++i)
    gload_lds16(x + agoff[i], (void*)(a_lds + (i * 256 + w * 64) * 4));
  #pragma unroll
  for (int j = 0; j < 6; ++j)
    gload_lds16(wt + bgoff[j], (void*)(b_lds + (j * 256 + w * 64) * 8));

  for (int k0 = 0; k0 < KS; k0 += 64) {
    __syncthreads();               // drains vmcnt(0): staged tile visible
    #pragma unroll
    for (int ks = 0; ks < 64; ks += 32) {
      const int m  = mw * 16 + ln;
      const int c0 = (ks >> 2) + 2 * quad;       // float-chunk of A fragment
      f32x4 v0 = *(const f32x4*)&a_lds[m * 64 + ((c0 ^ lsw) << 2)];
      f32x4 v1 = *(const f32x4*)&a_lds[m * 64 + (((c0 + 1) ^ lsw) << 2)];
      #pragma unroll
      for (int j = 0; j < 4; ++j) { ap.h[j] = f2bf(v0[j]); ap.h[4 + j] = f2bf(v1[j]); }
      s16x8 af = ap.v;
      const int cb = (ks >> 3) + quad;           // bf16-chunk of B fragment
      #pragma unroll
      for (int nt = 0; nt < 6; ++nt) {
        int n = n0 + nt * 16 + ln;
        s16x8 bf = *(const s16x8*)&b_lds[n * 64 + ((cb ^ lsw) << 3)];
        MFMA(acc[nt], af, bf);
      }
    }
    __syncthreads();               // all waves done reading before re-stage
    if (k0 + 64 < KS) {
      const int kn = k0 + 64;
      #pragma unroll
      for (int i = 0; i < 2; ++i)
        gload_lds16(x + agoff[i] + kn, (void*)(a_lds + (i * 256 + w * 64) * 4));
      #pragma unroll
      for (int j = 0; j < 6; ++j)
        gload_lds16(wt + bgoff[j] + kn, (void*)(b_lds + (j * 256 + w * 64) * 8));
    }
  }

  // fp32 partial epilogue (no scale/transpose — reduce handles that)
  float* pp = pbuf + (size_t)blockIdx.y * 16384 * 192;
  const int mm0 = m0 + mw * 16;
  #pragma unroll
  for (int nt = 0; nt < 6; ++nt) {
    const int ncol = n0 + nt * 16 + ln;
    #pragma unroll
    for (int r = 0; r < 4; ++r) {
      int row = mm0 + quad * 4 + r;       // C/D: row = quad*4+reg, col = lane&15
      pp[(size_t)row * 192 + ncol] = acc[nt][r];
    }
  }
}

// ---------------- reduce: sum 2 k-slices; emit qkvqk (Q scaled | K) + vT -------------
// blocks [0,1024): QK section, thread -> (row, 8 cols). blocks [1024,1536): V section,
// thread -> (b, d, 8 consecutive t) for coalesced vT writes.
__global__ __launch_bounds__(256) void qkv_reduce_kernel(
    const float* __restrict__ pbuf, unsigned short* __restrict__ qkvqk,
    unsigned short* __restrict__ vt) {
  const float* p0 = pbuf;
  const float* p1 = pbuf + (size_t)16384 * 192;
  const float QS = 0.18033688011112042f;  // (1/8) * log2(e)
  int id = blockIdx.x * 256 + threadIdx.x;

  if (blockIdx.x < 1024) {                // QK: 262144 threads = 16384 rows x 16 col8
    int row = id >> 4;
    int c8  = (id & 15) * 8;
    size_t o = (size_t)row * 192 + c8;
    f32x4 s0 = *(const f32x4*)(p0 + o)     + *(const f32x4*)(p1 + o);
    f32x4 s1 = *(const f32x4*)(p0 + o + 4) + *(const f32x4*)(p1 + o + 4);
    const float sc = (c8 < 64) ? QS : 1.0f;
    u16x4 h0, h1;
    #pragma unroll
    for (int j = 0; j < 4; ++j) { h0[j] = f2bf(s0[j] * sc); h1[j] = f2bf(s1[j] * sc); }
    *(u16x4*)(qkvqk + (size_t)row * 128 + c8)     = h0;
    *(u16x4*)(qkvqk + (size_t)row * 128 + c8 + 4) = h1;
  } else {                                // V: 131072 threads = 8 b x 64 d x 256 t8
    int v  = id - 262144;
    int b  = v >> 14;
    int d  = (v >> 8) & 63;
    int t8 = (v & 255) * 8;
    u16x4 h0, h1;
    #pragma unroll
    for (int j = 0; j < 8; ++j) {
      size_t o = (size_t)(b * TT + t8 + j) * 192 + 128 + d;
      float s = p0[o] + p1[o];
      if (j < 4) h0[j] = f2bf(s); else h1[j - 4] = f2bf(s);
    }
    unsigned short* dst = vt + ((size_t)b * 64 + d) * TT + t8;
    *(u16x4*)(dst)     = h0;
    *(u16x4*)(dst + 4) = h1;
  }
}

// ---------------- attn partial: 128-row q-supertile x 256-key chunk (R10) ------------
__global__ __launch_bounds__(256) void attn_part_kernel(
    const unsigned short* __restrict__ qkvqk, const unsigned short* __restrict__ vt,
    unsigned short* __restrict__ opart, float* __restrict__ ml) {
  // cumulative chunk counts per supertile: C[s] = sum_{u<s} (u+2)>>1
  const int Ctab[16] = {0,1,2,4,6,9,12,16,20,25,30,36,42,49,56,64};
  const int f  = blockIdx.x;       // 0..575
  const int bz = f / 72;
  const int rw = f - bz * 72;
  int s = 0;
  #pragma unroll
  for (int t = 1; t < 16; ++t) if (rw >= Ctab[t]) s = t;
  const int c = rw - Ctab[s];
  const int ntiles = min(4, 2 * s + 2 - 4 * c);   // in {2,4}
  const int qtA = 2 * s, qtB = 2 * s + 1;

  __shared__ __align__(16) unsigned short k_lds[256 * 64];   // 32 KB, swizzled chunks
  __shared__ __align__(16) unsigned short v_lds[64 * 256];   // 32 KB, swizzled chunks
  __shared__ __align__(16) unsigned short p_lds[64 * KST];   // 9 KB, padded

  const int tid  = threadIdx.x;
  const int w    = tid >> 6;
  const int lane = tid & 63;
  const int ln   = lane & 15;
  const int quad = lane >> 4;
  const int lsw  = ln & 7;         // read-side swizzle key
  const int bb   = bz * TT;
  const int kbase = c * 256;

  // ---- stage K: 2048 chunk-slots; slot s -> (row=s>>3, cc=s&7); data = cc ^ (row&7)
  #pragma unroll
  for (int i = 0; i < 8; ++i) {
    int base = (i * 4 + w) * 64;
    int slot = base + lane;
    int row = slot >> 3, cc = slot & 7;
    gload_lds16(qkvqk + (size_t)(bb + kbase + row) * 128 + 64 + ((cc ^ (row & 7)) << 3),
                (void*)(k_lds + base * 8));
  }
  // ---- stage V^T: 2048 chunk-slots; slot -> (d=s>>5, cc=s&31); data = cc ^ (d&7)
  #pragma unroll
  for (int i = 0; i < 8; ++i) {
    int base = (i * 4 + w) * 64;
    int slot = base + lane;
    int d = slot >> 5, cc = slot & 31;
    gload_lds16(vt + ((size_t)bz * 64 + d) * TT + kbase + ((cc ^ (d & 7)) << 3),
                (void*)(v_lds + base * 8));
  }

  // Q fragments for both q-tiles (log2-scaled already); A-layout m=lane&15, k=quad*8+j
  const unsigned short* qrowA = qkvqk + (size_t)(bb + qtA * 64 + w * 16 + ln) * 128;
  const unsigned short* qrowB = qrowA + 64 * 128;
  const s16x8 qfA0 = *(const s16x8*)(qrowA + quad * 8);
  const s16x8 qfA1 = *(const s16x8*)(qrowA + 32 + quad * 8);
  const s16x8 qfB0 = *(const s16x8*)(qrowB + quad * 8);
  const s16x8 qfB1 = *(const s16x8*)(qrowB + 32 + quad * 8);

  s16x8 ones;
  #pragma unroll
  for (int j = 0; j < 8; ++j) ones[j] = (short)0x3F80;  // bf16 1.0

  f32x4 acc_oA[4], acc_oB[4], acc_lA, acc_lB;
  #pragma unroll
  for (int i = 0; i < 4; ++i) {
    acc_oA[i] = (f32x4){0.f, 0.f, 0.f, 0.f};
    acc_oB[i] = (f32x4){0.f, 0.f, 0.f, 0.f};
  }
  acc_lA = (f32x4){0.f, 0.f, 0.f, 0.f};
  acc_lB = (f32x4){0.f, 0.f, 0.f, 0.f};

  const int qgA = qtA * 64 + w * 16 + quad * 4;
  const int qgB = qgA + 64;
  __syncthreads();  // drains vmcnt(0): K/V staged

  for (int ct = 0; ct < ntiles; ++ct) {
    const int ktg = c * 4 + ct;
    const int kc0 = quad;          // K frag chunk, kk=0
    const int kc1 = 4 + quad;      // K frag chunk, kk=32

    // ---------- q-tile A pass (skip if tile entirely above the diagonal) ----------
    if (ktg <= qtA) {
      const bool diag = (ktg == qtA);
      f32x4 acc_s[4];
      #pragma unroll
      for (int i = 0; i < 4; ++i) acc_s[i] = (f32x4){0.f, 0.f, 0.f, 0.f};
      #pragma unroll
      for (int ns = 0; ns < 4; ++ns) {
        const int krow = ct * 64 + ns * 16 + ln;
        s16x8 kf0 = *(const s16x8*)&k_lds[krow * 64 + ((kc0 ^ lsw) << 3)];
        s16x8 kf1 = *(const s16x8*)&k_lds[krow * 64 + ((kc1 ^ lsw) << 3)];
        MFMA(acc_s[ns], qfA0, kf0);
        MFMA(acc_s[ns], qfA1, kf1);
      }
      #pragma unroll
      for (int r = 0; r < 4; ++r) {
        const int qg = qgA + r;
        #pragma unroll
        for (int ns = 0; ns < 4; ++ns) {
          float sv = acc_s[ns][r];
          if (diag) {
            int kg = ktg * 64 + ns * 16 + ln;
            sv = (kg <= qg) ? sv : -1e30f;
          }
          p_lds[(w * 16 + quad * 4 + r) * KST + ns * 16 + ln] = f2bf(exp2f(sv));
        }
      }
      #pragma unroll
      for (int kk = 0; kk < 64; kk += 32) {
        s16x8 pf = *(const s16x8*)&p_lds[(w * 16 + ln) * KST + kk + quad * 8];
        MFMA(acc_lA, pf, ones);
        #pragma unroll
        for (int nt = 0; nt < 4; ++nt) {
          const int d  = nt * 16 + ln;
          const int sc = ct * 8 + (((kk >> 3) + quad) ^ lsw);
          s16x8 vf = *(const s16x8*)&v_lds[d * 256 + sc * 8];
          MFMA(acc_oA[nt], pf, vf);
        }
      }
      asm volatile("" ::: "memory");
    }

    // ---------- q-tile B pass (always: ktg <= 2s+1 = qtB by construction) ----------
    {
      const bool diag = (ktg == qtB);
      f32x4 acc_s[4];
      #pragma unroll
      for (int i = 0; i < 4; ++i) acc_s[i] = (f32x4){0.f, 0.f, 0.f, 0.f};
      #pragma unroll
      for (int ns = 0; ns < 4; ++ns) {
        const int krow = ct * 64 + ns * 16 + ln;
        s16x8 kf0 = *(const s16x8*)&k_lds[krow * 64 + ((kc0 ^ lsw) << 3)];
        s16x8 kf1 = *(const s16x8*)&k_lds[krow * 64 + ((kc1 ^ lsw) << 3)];
        MFMA(acc_s[ns], qfB0, kf0);
        MFMA(acc_s[ns], qfB1, kf1);
      }
      #pragma unroll
      for (int r = 0; r < 4; ++r) {
        const int qg = qgB + r;
        #pragma unroll
        for (int ns = 0; ns < 4; ++ns) {
          float sv = acc_s[ns][r];
          if (diag) {
            int kg = ktg * 64 + ns * 16 + ln;
            sv = (kg <= qg) ? sv : -1e30f;
          }
          p_lds[(w * 16 + quad * 4 + r) * KST + ns * 16 + ln] = f2bf(exp2f(sv));
        }
      }
      #pragma unroll
      for (int kk = 0; kk < 64; kk += 32) {
        s16x8 pf = *(const s16x8*)&p_lds[(w * 16 + ln) * KST + kk + quad * 8];
        MFMA(acc_lB, pf, ones);
        #pragma unroll
        for (int nt = 0; nt < 4; ++nt) {
          const int d  = nt * 16 + ln;
          const int sc = ct * 8 + (((kk >> 3) + quad) ^ lsw);
          s16x8 vf = *(const s16x8*)&v_lds[d * 256 + sc * 8];
          MFMA(acc_oB[nt], pf, vf);
        }
      }
      asm volatile("" ::: "memory");
    }
  }

  // epilogue: two partial slabs, keyed by (qt, c) with base = qt + 2g(g-1) + rq*g
  #pragma unroll
  for (int half = 0; half < 2; ++half) {
    const int qt = (half == 0) ? qtA : qtB;
    const int g  = qt >> 2, rq = qt & 3;
    const int base = qt + 2 * g * (g - 1) + rq * g;
    const size_t slab = (size_t)bz * 144 + base + c;
    unsigned short* op = opart + slab * 4096;
    const f32x4* ao = (half == 0) ? acc_oA : acc_oB;
    const f32x4  al = (half == 0) ? acc_lA : acc_lB;
    #pragma unroll
    for (int nt = 0; nt < 4; ++nt)
      #pragma unroll
      for (int r = 0; r < 4; ++r)
        op[(w * 16 + quad * 4 + r) * 64 + nt * 16 + ln] = f2bf(ao[nt][r]);
    if (ln == 0) {
      float* lp = ml + slab * 64;
      #pragma unroll
      for (int r = 0; r < 4; ++r)
        lp[w * 16 + quad * 4 + r] = al[r];
    }
  }
}

// ---------------- combine: weight-1 merge of <=8 chunks (unchanged) ------------------
__global__ __launch_bounds__(256) void attn_combine_kernel(
    const unsigned short* __restrict__ opart, const float* __restrict__ ml,
    float* __restrict__ out) {
  const int qt = blockIdx.x;
  const int bz = blockIdx.y;
  const int aq = qt >> 2, rq = qt & 3;
  const int nch = aq + 1;
  const int base = qt + 2 * aq * (aq - 1) + rq * aq;
  const size_t slab0 = (size_t)bz * 144 + base;

  const int tid = threadIdx.x;
  const int row = tid >> 2;
  const int ds  = (tid & 3) * 16;

  float L = 0.f;
  float acc[16];
  #pragma unroll
  for (int j = 0; j < 16; ++j) acc[j] = 0.f;
  #pragma unroll 8
  for (int ch = 0; ch < nch; ++ch) {
    L += ml[(slab0 + ch) * 64 + row];
    const unsigned short* op = opart + (slab0 + ch) * 4096 + row * 64 + ds;
    i32x4 v0 = *(const i32x4*)(op);
    i32x4 v1 = *(const i32x4*)(op + 8);
    #pragma unroll
    for (int j = 0; j < 4; ++j) {
      unsigned int u0 = (unsigned int)v0[j], u1 = (unsigned int)v1[j];
      acc[j * 2]         += __uint_as_float(u0 << 16);
      acc[j * 2 + 1]     += __uint_as_float(u0 & 0xffff0000u);
      acc[8 + j * 2]     += __uint_as_float(u1 << 16);
      acc[8 + j * 2 + 1] += __uint_as_float(u1 & 0xffff0000u);
    }
  }
  float inv = 1.0f / L;
  float* o = out + ((size_t)bz * TT + qt * 64 + row) * 64 + ds;
  #pragma unroll
  for (int j = 0; j < 16; ++j) o[j] = acc[j] * inv;
}

extern "C" void kernel_launch(void* const* d_in, const int* in_sizes, int n_in,
                              void* d_out, int out_size, void* d_ws, size_t ws_size,
                              hipStream_t stream) {
  const float* x  = (const float*)d_in[0];
  const float* wq = (const float*)d_in[1];
  const float* wk = (const float*)d_in[2];
  const float* wv = (const float*)d_in[3];
  float* out = (float*)d_out;

  char* ws = (char*)d_ws;
  unsigned short* wt    = (unsigned short*)(ws + WS_WT);
  unsigned short* qkvqk = (unsigned short*)(ws + WS_QK);
  unsigned short* vt    = (unsigned short*)(ws + WS_VT);
  unsigned short* opart = (unsigned short*)(ws + WS_OP);
  float*          ml    = (float*)(ws + WS_ML);
  float*          pbuf  = (float*)(ws + WS_P);

  pack_w_kernel<<<(192 * DM + 255) / 256, 256, 0, stream>>>(wq, wk, wv, wt);
  qkv_gemm_kernel<<<dim3(512, 2), 256, 0, stream>>>(x, wt, pbuf);
  qkv_reduce_kernel<<<1536, 256, 0, stream>>>(pbuf, qkvqk, vt);
  attn_part_kernel<<<NB * 72, 256, 0, stream>>>(qkvqk, vt, opart, ml);
  attn_combine_kernel<<<dim3(32, NB), 256, 0, stream>>>(opart, ml, out);
}

// Round 13
// 136.061 us; speedup vs baseline: 1.1959x; 1.1959x over previous
//
#include <hip/hip_runtime.h>

// B=8, T=2048, D_MODEL=1024, D_HEAD=64, fp32 in/out.
// pack  -> Wt bf16[192][1024]
// gemm  -> qkvqk bf16[16384][128] (Q log2-scaled | K), vT bf16[8][64][2048]
//          m97-style global_load_lds staging, XOR-swizzled LDS, BK=128 (8 drains)
// attn  -> split-K no-max log2 flash; 128-row q-supertile x 256-key chunk; K/V via
//          global_load_lds with XOR-swizzled global source addressing (R10)
// combine -> weight-1 merge of <=8 chunks per (b, 64-row q-tile)
#define TT   2048
#define DM   1024
#define DH   64
#define NB   8
#define BK   128   // gemm K-tile (8 barrier-drains instead of 16)
#define KST  72    // p_lds row stride (elems)

typedef __attribute__((ext_vector_type(4))) float          f32x4;
typedef __attribute__((ext_vector_type(4))) int            i32x4;
typedef __attribute__((ext_vector_type(4))) unsigned short u16x4;
typedef __attribute__((ext_vector_type(8))) short          s16x8;  // bf16x8 frag (4 VGPRs)

__device__ __forceinline__ unsigned short f2bf(float f) {  // RNE fp32->bf16
  unsigned int u = __float_as_uint(f);
  u += 0x7fffu + ((u >> 16) & 1u);
  return (unsigned short)(u >> 16);
}

#define MFMA(acc, a, b) \
  (acc) = __builtin_amdgcn_mfma_f32_16x16x32_bf16((a), (b), (acc), 0, 0, 0)

// Async global->LDS DMA, 16B/lane. LDS dest is wave-uniform base + lane*16.
__device__ __forceinline__ void gload_lds16(const void* g, void* l) {
  __builtin_amdgcn_global_load_lds(
      (const __attribute__((address_space(1))) void*)g,
      (__attribute__((address_space(3))) void*)l, 16, 0, 0);
}

// ws layout (bytes)
#define WS_WT    0u
#define WS_QK    393216u     // 16384*128*2 = 4,194,304
#define WS_VT    4587520u    // 8*64*2048*2 = 2,097,152
#define WS_OP    6684672u    // 8*144*4096*2 = 9,437,184 (bf16 partial O)
#define WS_ML    16121856u   // 8*144*64*4  = 294,912   (f32 l per row)

// ---------------- pack: W_Q|W_K|W_V fp32[1024][64] -> Wt bf16[192][1024] -------------
__global__ __launch_bounds__(256) void pack_w_kernel(
    const float* __restrict__ wq, const float* __restrict__ wk,
    const float* __restrict__ wv, unsigned short* __restrict__ wt) {
  int idx = blockIdx.x * 256 + threadIdx.x;
  if (idx >= 192 * DM) return;
  int n = idx >> 10;
  int k = idx & (DM - 1);
  const float* src = (n < 64) ? wq : ((n < 128) ? wk : wv);
  wt[(size_t)n * DM + k] = f2bf(src[(size_t)k * DH + (n & 63)]);
}

// ---------------- QKV GEMM (m97 structure, BK=128) -----------------------------------
// 512 blocks x 256 thr (2 blocks/CU: LDS 64 KB x 2 = 128 <= 160 KB). Block = 32 rows x
// 192 cols, K-step 128 -> 8 vmcnt-drain barriers (was 16). A fp32 + B bf16 staged by
// global_load_lds into XOR-swizzled LDS (swizzle in the low 3 chunk bits; reads
// un-swizzle with ^lsw, 2-way bank aliasing = free). Wave = 16 rows x 96 cols.
__global__ __launch_bounds__(256) void qkv_gemm_kernel(
    const float* __restrict__ x, const unsigned short* __restrict__ wt,
    unsigned short* __restrict__ qkvqk, unsigned short* __restrict__ vt) {
  __shared__ __align__(16) float          a_lds[32 * BK];    // 16 KB, swizzled chunks
  __shared__ __align__(16) unsigned short b_lds[192 * BK];   // 48 KB, swizzled chunks

  const int tid  = threadIdx.x;
  const int lane = tid & 63;
  const int w    = tid >> 6;
  const int ln   = lane & 15;
  const int quad = lane >> 4;
  const int mw   = w & 1;
  const int nw   = w >> 1;
  const int m0   = blockIdx.x * 32;
  const int n0   = nw * 96;
  const int lsw  = ln & 7;          // read-side swizzle key

  // A: 32 rows x 32 chunks (16B = 4 fp32). 1024 slots, 4 DMAs/wave.
  int agoff[4];
  #pragma unroll
  for (int i = 0; i < 4; ++i) {
    int s = i * 256 + w * 64 + lane;
    int m = s >> 5, cc = s & 31;
    agoff[i] = (m0 + m) * DM + ((cc ^ (m & 7)) << 2);
  }
  // B: 192 rows x 16 chunks (16B = 8 bf16). 3072 slots, 12 DMAs/wave.
  int bgoff[12];
  #pragma unroll
  for (int j = 0; j < 12; ++j) {
    int s = j * 256 + w * 64 + lane;
    int n = s >> 4, cc = s & 15;
    bgoff[j] = n * DM + ((cc ^ (n & 7)) << 3);
  }

  f32x4 acc[6];
  #pragma unroll
  for (int i = 0; i < 6; ++i) acc[i] = (f32x4){0.f, 0.f, 0.f, 0.f};
  union { s16x8 v; unsigned short h[8]; } ap;

  // prologue stage of tile 0
  #pragma unroll
  for (int i = 0; i < 4; ++i)
    gload_lds16(x + agoff[i], (void*)(a_lds + (i * 256 + w * 64) * 4));
  #pragma unroll
  for (int j = 0; j < 12; ++j)
    gload_lds16(wt + bgoff[j], (void*)(b_lds + (j * 256 + w * 64) * 8));

  for (int k0 = 0; k0 < DM; k0 += BK) {
    __syncthreads();               // drains vmcnt(0): staged tile visible
    #pragma unroll
    for (int ks = 0; ks < BK; ks += 32) {
      const int m  = mw * 16 + ln;
      const int c0 = (ks >> 2) + 2 * quad;       // float-chunk of A fragment
      f32x4 v0 = *(const f32x4*)&a_lds[m * BK + ((c0 ^ lsw) << 2)];
      f32x4 v1 = *(const f32x4*)&a_lds[m * BK + (((c0 + 1) ^ lsw) << 2)];
      #pragma unroll
      for (int j = 0; j < 4; ++j) { ap.h[j] = f2bf(v0[j]); ap.h[4 + j] = f2bf(v1[j]); }
      s16x8 af = ap.v;
      const int cb = (ks >> 3) + quad;           // bf16-chunk of B fragment
      #pragma unroll
      for (int nt = 0; nt < 6; ++nt) {
        int n = n0 + nt * 16 + ln;
        s16x8 bf = *(const s16x8*)&b_lds[n * BK + ((cb ^ lsw) << 3)];
        MFMA(acc[nt], af, bf);
      }
    }
    __syncthreads();               // all waves done reading before re-stage
    if (k0 + BK < DM) {
      const int kn = k0 + BK;
      #pragma unroll
      for (int i = 0; i < 4; ++i)
        gload_lds16(x + agoff[i] + kn, (void*)(a_lds + (i * 256 + w * 64) * 4));
      #pragma unroll
      for (int j = 0; j < 12; ++j)
        gload_lds16(wt + bgoff[j] + kn, (void*)(b_lds + (j * 256 + w * 64) * 8));
    }
  }

  const float QS = 0.18033688011112042f;  // (1/8) * log2(e)
  const int mm0 = m0 + mw * 16;
  const int bz  = mm0 >> 11;
  const int tb  = (mm0 & 2047) + quad * 4;
  #pragma unroll
  for (int nt = 0; nt < 6; ++nt) {
    const int ncol = n0 + nt * 16 + ln;
    if (ncol < 128) {                     // Q (scaled) | K -> qkvqk
      const float sc = (ncol < 64) ? QS : 1.0f;
      #pragma unroll
      for (int r = 0; r < 4; ++r) {
        int row = mm0 + quad * 4 + r;     // C/D: row = quad*4+reg, col = lane&15
        qkvqk[(size_t)row * 128 + ncol] = f2bf(acc[nt][r] * sc);
      }
    } else {                              // V -> vT[b][d][t]
      int d = ncol - 128;
      u16x4 h;
      #pragma unroll
      for (int r = 0; r < 4; ++r) h[r] = f2bf(acc[nt][r]);
      *(u16x4*)(vt + ((size_t)bz * 64 + d) * TT + tb) = h;
    }
  }
}

// ---------------- attn partial: 128-row q-supertile x 256-key chunk (R10) ------------
__global__ __launch_bounds__(256) void attn_part_kernel(
    const unsigned short* __restrict__ qkvqk, const unsigned short* __restrict__ vt,
    unsigned short* __restrict__ opart, float* __restrict__ ml) {
  // cumulative chunk counts per supertile: C[s] = sum_{u<s} (u+2)>>1
  const int Ctab[16] = {0,1,2,4,6,9,12,16,20,25,30,36,42,49,56,64};
  const int f  = blockIdx.x;       // 0..575
  const int bz = f / 72;
  const int rw = f - bz * 72;
  int s = 0;
  #pragma unroll
  for (int t = 1; t < 16; ++t) if (rw >= Ctab[t]) s = t;
  const int c = rw - Ctab[s];
  const int ntiles = min(4, 2 * s + 2 - 4 * c);   // in {2,4}
  const int qtA = 2 * s, qtB = 2 * s + 1;

  __shared__ __align__(16) unsigned short k_lds[256 * 64];   // 32 KB, swizzled chunks
  __shared__ __align__(16) unsigned short v_lds[64 * 256];   // 32 KB, swizzled chunks
  __shared__ __align__(16) unsigned short p_lds[64 * KST];   // 9 KB, padded

  const int tid  = threadIdx.x;
  const int w    = tid >> 6;
  const int lane = tid & 63;
  const int ln   = lane & 15;
  const int quad = lane >> 4;
  const int lsw  = ln & 7;         // read-side swizzle key
  const int bb   = bz * TT;
  const int kbase = c * 256;

  // ---- stage K: 2048 chunk-slots; slot s -> (row=s>>3, cc=s&7); data = cc ^ (row&7)
  #pragma unroll
  for (int i = 0; i < 8; ++i) {
    int base = (i * 4 + w) * 64;
    int slot = base + lane;
    int row = slot >> 3, cc = slot & 7;
    gload_lds16(qkvqk + (size_t)(bb + kbase + row) * 128 + 64 + ((cc ^ (row & 7)) << 3),
                (void*)(k_lds + base * 8));
  }
  // ---- stage V^T: 2048 chunk-slots; slot -> (d=s>>5, cc=s&31); data = cc ^ (d&7)
  #pragma unroll
  for (int i = 0; i < 8; ++i) {
    int base = (i * 4 + w) * 64;
    int slot = base + lane;
    int d = slot >> 5, cc = slot & 31;
    gload_lds16(vt + ((size_t)bz * 64 + d) * TT + kbase + ((cc ^ (d & 7)) << 3),
                (void*)(v_lds + base * 8));
  }

  // Q fragments for both q-tiles (log2-scaled already); A-layout m=lane&15, k=quad*8+j
  const unsigned short* qrowA = qkvqk + (size_t)(bb + qtA * 64 + w * 16 + ln) * 128;
  const unsigned short* qrowB = qrowA + 64 * 128;
  const s16x8 qfA0 = *(const s16x8*)(qrowA + quad * 8);
  const s16x8 qfA1 = *(const s16x8*)(qrowA + 32 + quad * 8);
  const s16x8 qfB0 = *(const s16x8*)(qrowB + quad * 8);
  const s16x8 qfB1 = *(const s16x8*)(qrowB + 32 + quad * 8);

  s16x8 ones;
  #pragma unroll
  for (int j = 0; j < 8; ++j) ones[j] = (short)0x3F80;  // bf16 1.0

  f32x4 acc_oA[4], acc_oB[4], acc_lA, acc_lB;
  #pragma unroll
  for (int i = 0; i < 4; ++i) {
    acc_oA[i] = (f32x4){0.f, 0.f, 0.f, 0.f};
    acc_oB[i] = (f32x4){0.f, 0.f, 0.f, 0.f};
  }
  acc_lA = (f32x4){0.f, 0.f, 0.f, 0.f};
  acc_lB = (f32x4){0.f, 0.f, 0.f, 0.f};

  const int qgA = qtA * 64 + w * 16 + quad * 4;
  const int qgB = qgA + 64;
  __syncthreads();  // drains vmcnt(0): K/V staged

  for (int ct = 0; ct < ntiles; ++ct) {
    const int ktg = c * 4 + ct;
    const int kc0 = quad;          // K frag chunk, kk=0
    const int kc1 = 4 + quad;      // K frag chunk, kk=32

    // ---------- q-tile A pass (skip if tile entirely above the diagonal) ----------
    if (ktg <= qtA) {
      const bool diag = (ktg == qtA);
      f32x4 acc_s[4];
      #pragma unroll
      for (int i = 0; i < 4; ++i) acc_s[i] = (f32x4){0.f, 0.f, 0.f, 0.f};
      #pragma unroll
      for (int ns = 0; ns < 4; ++ns) {
        const int krow = ct * 64 + ns * 16 + ln;
        s16x8 kf0 = *(const s16x8*)&k_lds[krow * 64 + ((kc0 ^ lsw) << 3)];
        s16x8 kf1 = *(const s16x8*)&k_lds[krow * 64 + ((kc1 ^ lsw) << 3)];
        MFMA(acc_s[ns], qfA0, kf0);
        MFMA(acc_s[ns], qfA1, kf1);
      }
      #pragma unroll
      for (int r = 0; r < 4; ++r) {
        const int qg = qgA + r;
        #pragma unroll
        for (int ns = 0; ns < 4; ++ns) {
          float sv = acc_s[ns][r];
          if (diag) {
            int kg = ktg * 64 + ns * 16 + ln;
            sv = (kg <= qg) ? sv : -1e30f;
          }
          p_lds[(w * 16 + quad * 4 + r) * KST + ns * 16 + ln] = f2bf(exp2f(sv));
        }
      }
      #pragma unroll
      for (int kk = 0; kk < 64; kk += 32) {
        s16x8 pf = *(const s16x8*)&p_lds[(w * 16 + ln) * KST + kk + quad * 8];
        MFMA(acc_lA, pf, ones);
        #pragma unroll
        for (int nt = 0; nt < 4; ++nt) {
          const int d  = nt * 16 + ln;
          const int sc = ct * 8 + (((kk >> 3) + quad) ^ lsw);
          s16x8 vf = *(const s16x8*)&v_lds[d * 256 + sc * 8];
          MFMA(acc_oA[nt], pf, vf);
        }
      }
      asm volatile("" ::: "memory");
    }

    // ---------- q-tile B pass (always: ktg <= 2s+1 = qtB by construction) ----------
    {
      const bool diag = (ktg == qtB);
      f32x4 acc_s[4];
      #pragma unroll
      for (int i = 0; i < 4; ++i) acc_s[i] = (f32x4){0.f, 0.f, 0.f, 0.f};
      #pragma unroll
      for (int ns = 0; ns < 4; ++ns) {
        const int krow = ct * 64 + ns * 16 + ln;
        s16x8 kf0 = *(const s16x8*)&k_lds[krow * 64 + ((kc0 ^ lsw) << 3)];
        s16x8 kf1 = *(const s16x8*)&k_lds[krow * 64 + ((kc1 ^ lsw) << 3)];
        MFMA(acc_s[ns], qfB0, kf0);
        MFMA(acc_s[ns], qfB1, kf1);
      }
      #pragma unroll
      for (int r = 0; r < 4; ++r) {
        const int qg = qgB + r;
        #pragma unroll
        for (int ns = 0; ns < 4; ++ns) {
          float sv = acc_s[ns][r];
          if (diag) {
            int kg = ktg * 64 + ns * 16 + ln;
            sv = (kg <= qg) ? sv : -1e30f;
          }
          p_lds[(w * 16 + quad * 4 + r) * KST + ns * 16 + ln] = f2bf(exp2f(sv));
        }
      }
      #pragma unroll
      for (int kk = 0; kk < 64; kk += 32) {
        s16x8 pf = *(const s16x8*)&p_lds[(w * 16 + ln) * KST + kk + quad * 8];
        MFMA(acc_lB, pf, ones);
        #pragma unroll
        for (int nt = 0; nt < 4; ++nt) {
          const int d  = nt * 16 + ln;
          const int sc = ct * 8 + (((kk >> 3) + quad) ^ lsw);
          s16x8 vf = *(const s16x8*)&v_lds[d * 256 + sc * 8];
          MFMA(acc_oB[nt], pf, vf);
        }
      }
      asm volatile("" ::: "memory");
    }
  }

  // epilogue: two partial slabs, keyed by (qt, c) with base = qt + 2g(g-1) + rq*g
  #pragma unroll
  for (int half = 0; half < 2; ++half) {
    const int qt = (half == 0) ? qtA : qtB;
    const int g  = qt >> 2, rq = qt & 3;
    const int base = qt + 2 * g * (g - 1) + rq * g;
    const size_t slab = (size_t)bz * 144 + base + c;
    unsigned short* op = opart + slab * 4096;
    const f32x4* ao = (half == 0) ? acc_oA : acc_oB;
    const f32x4  al = (half == 0) ? acc_lA : acc_lB;
    #pragma unroll
    for (int nt = 0; nt < 4; ++nt)
      #pragma unroll
      for (int r = 0; r < 4; ++r)
        op[(w * 16 + quad * 4 + r) * 64 + nt * 16 + ln] = f2bf(ao[nt][r]);
    if (ln == 0) {
      float* lp = ml + slab * 64;
      #pragma unroll
      for (int r = 0; r < 4; ++r)
        lp[w * 16 + quad * 4 + r] = al[r];
    }
  }
}

// ---------------- combine: weight-1 merge of <=8 chunks (unchanged) ------------------
__global__ __launch_bounds__(256) void attn_combine_kernel(
    const unsigned short* __restrict__ opart, const float* __restrict__ ml,
    float* __restrict__ out) {
  const int qt = blockIdx.x;
  const int bz = blockIdx.y;
  const int aq = qt >> 2, rq = qt & 3;
  const int nch = aq + 1;
  const int base = qt + 2 * aq * (aq - 1) + rq * aq;
  const size_t slab0 = (size_t)bz * 144 + base;

  const int tid = threadIdx.x;
  const int row = tid >> 2;
  const int ds  = (tid & 3) * 16;

  float L = 0.f;
  float acc[16];
  #pragma unroll
  for (int j = 0; j < 16; ++j) acc[j] = 0.f;
  #pragma unroll 8
  for (int ch = 0; ch < nch; ++ch) {
    L += ml[(slab0 + ch) * 64 + row];
    const unsigned short* op = opart + (slab0 + ch) * 4096 + row * 64 + ds;
    i32x4 v0 = *(const i32x4*)(op);
    i32x4 v1 = *(const i32x4*)(op + 8);
    #pragma unroll
    for (int j = 0; j < 4; ++j) {
      unsigned int u0 = (unsigned int)v0[j], u1 = (unsigned int)v1[j];
      acc[j * 2]         += __uint_as_float(u0 << 16);
      acc[j * 2 + 1]     += __uint_as_float(u0 & 0xffff0000u);
      acc[8 + j * 2]     += __uint_as_float(u1 << 16);
      acc[8 + j * 2 + 1] += __uint_as_float(u1 & 0xffff0000u);
    }
  }
  float inv = 1.0f / L;
  float* o = out + ((size_t)bz * TT + qt * 64 + row) * 64 + ds;
  #pragma unroll
  for (int j = 0; j < 16; ++j) o[j] = acc[j] * inv;
}

extern "C" void kernel_launch(void* const* d_in, const int* in_sizes, int n_in,
                              void* d_out, int out_size, void* d_ws, size_t ws_size,
                              hipStream_t stream) {
  const float* x  = (const float*)d_in[0];
  const float* wq = (const float*)d_in[1];
  const float* wk = (const float*)d_in[2];
  const float* wv = (const float*)d_in[3];
  float* out = (float*)d_out;

  char* ws = (char*)d_ws;
  unsigned short* wt    = (unsigned short*)(ws + WS_WT);
  unsigned short* qkvqk = (unsigned short*)(ws + WS_QK);
  unsigned short* vt    = (unsigned short*)(ws + WS_VT);
  unsigned short* opart = (unsigned short*)(ws + WS_OP);
  float*          ml    = (float*)(ws + WS_ML);

  pack_w_kernel<<<(192 * DM + 255) / 256, 256, 0, stream>>>(wq, wk, wv, wt);
  qkv_gemm_kernel<<<NB * TT / 32, 256, 0, stream>>>(x, wt, qkvqk, vt);
  attn_part_kernel<<<NB * 72, 256, 0, stream>>>(qkvqk, vt, opart, ml);
  attn_combine_kernel<<<dim3(32, NB), 256, 0, stream>>>(opart, ml, out);
}